// Round 9
// baseline (705.439 us; speedup 1.0000x reference)
//
#include <hip/hip_runtime.h>
#include <hip/hip_bf16.h>
#include <hip/hip_cooperative_groups.h>
#include <stdint.h>

namespace cg = cooperative_groups;

typedef __attribute__((ext_vector_type(8))) short bfrag;
typedef __attribute__((ext_vector_type(4))) short bfrag4;
typedef __attribute__((ext_vector_type(4))) float f32x4;
typedef __attribute__((ext_vector_type(2))) float f32x2;
typedef __attribute__((ext_vector_type(2))) unsigned int u32x2;

__device__ inline short f2bf(float f) {
  union { float f; uint32_t u; } v; v.f = f;
  uint32_t u = v.u;
  uint32_t r = (u + 0x7fffu + ((u >> 16) & 1u)) >> 16;
  return (short)r;
}
__device__ inline float bf2f(short s) {
  return __builtin_bit_cast(float, (uint32_t)((uint32_t)(uint16_t)s << 16));
}

#if __has_builtin(__builtin_amdgcn_cvt_pk_bf16_f32)
typedef __attribute__((ext_vector_type(2))) __bf16 bf16x2_t;
__device__ inline uint32_t pack_bf16(float a, float b) {
  bf16x2_t r = __builtin_amdgcn_cvt_pk_bf16_f32(a, b);
  return __builtin_bit_cast(uint32_t, r);
}
#else
__device__ inline uint32_t pack_bf16(float a, float b) {
  uint32_t ua = __builtin_bit_cast(uint32_t, a) + 0x8000u;
  uint32_t ub = __builtin_bit_cast(uint32_t, b) + 0x8000u;
  return __builtin_amdgcn_perm(ub, ua, 0x07060302);
}
#endif

// Single persistent cooperative kernel: 6 phases separated by grid.sync().
// Phase work is grid-stride so correctness holds for any co-resident grid G.
// __launch_bounds__(256,4): VGPR cap 128 (max live ~100, no spill) ->
// >=4 blocks/CU guaranteed -> G=1024 co-resident.
__global__ __launch_bounds__(256, 4) void fused_kernel(
    const float* __restrict__ x, const int* __restrict__ t,
    const float* __restrict__ emb_table, const float* __restrict__ ada_w,
    const float* __restrict__ ada_b, const float* __restrict__ qkv_w,
    const float* __restrict__ qkv_b, const float* __restrict__ proj_w,
    const float* __restrict__ proj_b, float* __restrict__ scsh,
    short* __restrict__ qkv_wt, short* __restrict__ proj_wt,
    short* __restrict__ xb, short* __restrict__ qk, short* __restrict__ vT,
    short* __restrict__ attn_out, short* __restrict__ OpB,
    float* __restrict__ lpart, float* __restrict__ out) {
  cg::grid_group grid = cg::this_grid();
  __shared__ __align__(16) char smem_raw[18944];
  const int tid = threadIdx.x;
  const int bx = blockIdx.x;
  const int G = gridDim.x;
  const float QS = 0.17677669529663687f * 1.4426950408889634f;  // scale*log2e

  // ---------------- phase 0: ada (16 blocks) ------------------------------
  if (bx < 16) {
    float* se = (float*)smem_raw;
    float* part = se + 256;
    int b = bx >> 3, ox = bx & 7;
    int tt = t[b];
    float e = emb_table[tt * 256 + tid];
    se[tid] = e / (1.f + __expf(-e));
    __syncthreads();
    int ol = tid & 63, kc = tid >> 6;
    int o = ox * 64 + ol;
    float acc = 0.f;
#pragma unroll 8
    for (int k = kc * 64; k < (kc + 1) * 64; ++k) acc += se[k] * ada_w[k * 512 + o];
    part[tid] = acc;
    __syncthreads();
    if (tid < 64) {
      int oo = ox * 64 + tid;
      scsh[b * 512 + oo] =
          part[tid] + part[64 + tid] + part[128 + tid] + part[192 + tid] + ada_b[oo];
    }
  }
  __threadfence();
  grid.sync();

  // ---------------- phase 1: weight transposes (64) + LN (2048) -----------
  for (int it = bx; it < 2112; it += G) {
    if (it < 64) {
      const float* W; short* Wt; int N, lb;
      if (it < 48) { W = qkv_w; Wt = qkv_wt; N = 768; lb = it; }
      else         { W = proj_w; Wt = proj_wt; N = 256; lb = it - 48; }
      float (*tile)[65] = (float(*)[65])smem_raw;
      int k0 = (lb & 3) * 64, n0 = (lb >> 2) * 64;
      int r = tid >> 2, c0 = (tid & 3) * 16;
      const float* src = W + (long)(k0 + r) * N + n0 + c0;
#pragma unroll
      for (int j = 0; j < 16; j += 4) {
        float4 v = *(const float4*)(src + j);
        tile[r][c0 + j] = v.x; tile[r][c0 + j + 1] = v.y;
        tile[r][c0 + j + 2] = v.z; tile[r][c0 + j + 3] = v.w;
      }
      __syncthreads();
      int nl = tid >> 2, kc = (tid & 3) * 16;
      short outv[16];
#pragma unroll
      for (int j = 0; j < 16; ++j) outv[j] = f2bf(tile[kc + j][nl]);
      short* dst = Wt + (long)(n0 + nl) * 256 + k0 + kc;
      *(bfrag*)dst = *(bfrag*)&outv[0];
      *(bfrag*)(dst + 8) = *(bfrag*)&outv[8];
      __syncthreads();
    } else {
      int row = (it - 64) * 4 + (tid >> 6);
      int b = row >> 12;
      int lane = tid & 63;
      float4 v = *(const float4*)(x + (long)row * 256 + lane * 4);
      float s = v.x + v.y + v.z + v.w;
      float sq = v.x * v.x + v.y * v.y + v.z * v.z + v.w * v.w;
#pragma unroll
      for (int off = 32; off > 0; off >>= 1) {
        s += __shfl_xor(s, off);
        sq += __shfl_xor(sq, off);
      }
      float mu = s * (1.f / 256.f);
      float var = sq * (1.f / 256.f) - mu * mu;
      float rstd = rsqrtf(var + 1e-5f);
      const float* scp = scsh + b * 512 + lane * 4;
      float4 sc = *(const float4*)scp;
      float4 sh = *(const float4*)(scp + 256);
      float y0 = (v.x - mu) * rstd * (1.f + sc.x) + sh.x;
      float y1 = (v.y - mu) * rstd * (1.f + sc.y) + sh.y;
      float y2 = (v.z - mu) * rstd * (1.f + sc.z) + sh.z;
      float y3 = (v.w - mu) * rstd * (1.f + sc.w) + sh.w;
      u32x2 o; o.x = pack_bf16(y0, y1); o.y = pack_bf16(y2, y3);
      *(u32x2*)&xb[(long)row * 256 + lane * 4] = o;
    }
  }
  __threadfence();
  grid.sync();

  // ---------------- phase 2: QKV GEMM (768 items, 128x64 tile) ------------
  {
    short* As = (short*)smem_raw;        // 128*40
    short* Bs = As + 128 * 40;           // 64*40
    const int w = tid >> 6, lane = tid & 63, l16 = lane & 15, quad = lane >> 4;
    const int ar = tid >> 1, ak = (tid & 1) * 16;
    const int br = tid >> 2, bk = (tid & 3) * 8;
    for (int it = bx; it < 768; it += G) {
      int mt = it & 63, nt = it >> 6;
      f32x4 acc[2][4] = {};
      const short* Arow = xb + (long)(mt * 128 + ar) * 256 + ak;
      const short* Brow = qkv_wt + (long)(nt * 64 + br) * 256 + bk;
      bfrag a8a = *(const bfrag*)Arow;
      bfrag a8b = *(const bfrag*)(Arow + 8);
      bfrag b8  = *(const bfrag*)Brow;
      for (int kk = 0; kk < 8; ++kk) {
        __syncthreads();
        *(bfrag*)&As[ar * 40 + ak] = a8a;
        *(bfrag*)&As[ar * 40 + ak + 8] = a8b;
        *(bfrag*)&Bs[br * 40 + bk] = b8;
        __syncthreads();
        int kn = (kk < 7) ? (kk + 1) : 7;
        a8a = *(const bfrag*)(Arow + kn * 32);
        a8b = *(const bfrag*)(Arow + kn * 32 + 8);
        b8  = *(const bfrag*)(Brow + kn * 32);
        bfrag a0 = *(const bfrag*)&As[(w * 32 + l16) * 40 + quad * 8];
        bfrag a1 = *(const bfrag*)&As[(w * 32 + 16 + l16) * 40 + quad * 8];
#pragma unroll
        for (int c = 0; c < 4; ++c) {
          bfrag bf = *(const bfrag*)&Bs[(c * 16 + l16) * 40 + quad * 8];
          acc[0][c] = __builtin_amdgcn_mfma_f32_16x16x32_bf16(a0, bf, acc[0][c], 0, 0, 0);
          acc[1][c] = __builtin_amdgcn_mfma_f32_16x16x32_bf16(a1, bf, acc[1][c], 0, 0, 0);
        }
      }
      const int rowb = mt * 128 + w * 32 + quad * 4;
      if (nt < 8) {  // Q,K -> qk (pitch 512), Q pre-scaled by QS
#pragma unroll
        for (int rg = 0; rg < 2; ++rg) {
          int row0 = rowb + rg * 16;
#pragma unroll
          for (int c = 0; c < 4; ++c) {
            int col = nt * 64 + c * 16 + l16;
            float bv = qkv_b[col];
            float mult = (col < 256) ? QS : 1.0f;
#pragma unroll
            for (int r = 0; r < 4; ++r)
              qk[(long)(row0 + r) * 512 + col] = f2bf((acc[rg][c][r] + bv) * mult);
          }
        }
      } else {  // V -> vT[bh][d][key]
        const int bb = mt >> 5;
#pragma unroll
        for (int rg = 0; rg < 2; ++rg) {
          int keyl = (rowb + rg * 16) & 4095;
#pragma unroll
          for (int c = 0; c < 4; ++c) {
            int col = nt * 64 + c * 16 + l16;
            float bv = qkv_b[col];
            int d = col - 512;
            u32x2 dd;
            dd.x = pack_bf16(acc[rg][c][0] + bv, acc[rg][c][1] + bv);
            dd.y = pack_bf16(acc[rg][c][2] + bv, acc[rg][c][3] + bv);
            *(u32x2*)&vT[((long)(bb * 8 + (d >> 5)) * 32 + (d & 31)) * 4096 + keyl] = dd;
          }
        }
      }
    }
  }
  __threadfence();
  grid.sync();

  // ---------------- phase 3: attention (1024 items, 4 q-groups/wave) ------
  {
    short* KsB = (short*)smem_raw;      // 2 x 64*40
    short* VtB = KsB + 2 * 2560;        // 2 x 32*68
    const int w = tid >> 6, lane = tid & 63, l16 = lane & 15, quad = lane >> 4;
    const int si = tid >> 2, sk = (tid & 3) * 8;
    const int vrow = tid >> 3, vcol = (tid & 7) * 8;
    for (int it = bx; it < 1024; it += G) {
      const int qt = it & 15;
      const int bh = (it >> 4) & 15;
      const int ks = it >> 8;
      const int b = bh >> 3, hh = bh & 7;
      const long rowbase = (long)b * 4096;
      const int qrow0 = qt * 256 + w * 64 + l16;
      bfrag qf[4];
#pragma unroll
      for (int g = 0; g < 4; ++g)
        qf[g] = *(const bfrag*)&qk[(rowbase + qrow0 + g * 16) * 512 + hh * 32 + quad * 8];
      f32x4 o0[4] = {}, o1[4] = {};
      f32x2 lsum[4] = {};
      const short* ksrc = qk + rowbase * 512 + 256 + hh * 32 + (long)si * 512 + sk;
      const short* vsrc = vT + ((long)bh * 32 + vrow) * 4096 + vcol;
      const int kt0 = ks * 16;
      bfrag k8 = *(const bfrag*)(ksrc + (long)kt0 * 64 * 512);
      bfrag v8 = *(const bfrag*)(vsrc + kt0 * 64);
      int buf = 0;
      for (int i = 0; i < 16; ++i) {
        *(bfrag*)&KsB[buf * 2560 + si * 40 + sk] = k8;
        *(bfrag*)&VtB[buf * 2176 + vrow * 68 + vcol] = v8;
        __syncthreads();
        int nn = (i < 15) ? (i + 1) : 15;
        k8 = *(const bfrag*)(ksrc + (long)(kt0 + nn) * 64 * 512);
        v8 = *(const bfrag*)(vsrc + (kt0 + nn) * 64);
#pragma unroll
        for (int nt = 0; nt < 4; ++nt) {
          bfrag kf = *(const bfrag*)&KsB[buf * 2560 + (nt * 16 + l16) * 40 + quad * 8];
          f32x4 z = {0,0,0,0};
          f32x4 s[4];
          s[0] = __builtin_amdgcn_mfma_f32_16x16x32_bf16(kf, qf[0], z, 0, 0, 0);
          s[1] = __builtin_amdgcn_mfma_f32_16x16x32_bf16(kf, qf[1], z, 0, 0, 0);
          s[2] = __builtin_amdgcn_mfma_f32_16x16x32_bf16(kf, qf[2], z, 0, 0, 0);
          s[3] = __builtin_amdgcn_mfma_f32_16x16x32_bf16(kf, qf[3], z, 0, 0, 0);
          bfrag4 pb[4];
#pragma unroll
          for (int g = 0; g < 4; ++g) {
            float p0 = __builtin_amdgcn_exp2f(s[g][0]);
            float p1 = __builtin_amdgcn_exp2f(s[g][1]);
            float p2 = __builtin_amdgcn_exp2f(s[g][2]);
            float p3 = __builtin_amdgcn_exp2f(s[g][3]);
            f32x2 pa = {p0, p1}, pc = {p2, p3};
            lsum[g] += pa; lsum[g] += pc;
            u32x2 pk; pk.x = pack_bf16(p0, p1); pk.y = pack_bf16(p2, p3);
            pb[g] = __builtin_bit_cast(bfrag4, pk);
          }
          bfrag4 va = *(const bfrag4*)&VtB[buf * 2176 + l16 * 68 + nt * 16 + quad * 4];
          bfrag4 vb = *(const bfrag4*)&VtB[buf * 2176 + (16 + l16) * 68 + nt * 16 + quad * 4];
#pragma unroll
          for (int g = 0; g < 4; ++g) {
            o0[g] = __builtin_amdgcn_mfma_f32_16x16x16bf16_1k(va, pb[g], o0[g], 0, 0, 0);
            o1[g] = __builtin_amdgcn_mfma_f32_16x16x16bf16_1k(vb, pb[g], o1[g], 0, 0, 0);
          }
        }
        buf ^= 1;
      }
#pragma unroll
      for (int g = 0; g < 4; ++g) {
        float ls = lsum[g].x + lsum[g].y;
        ls += __shfl_xor(ls, 16); ls += __shfl_xor(ls, 32);
        const long pbase = (((long)ks * 16 + bh) * 4096 + qrow0 + g * 16) * 32;
        u32x2 dA, dB;
        dA.x = pack_bf16(o0[g][0], o0[g][1]); dA.y = pack_bf16(o0[g][2], o0[g][3]);
        dB.x = pack_bf16(o1[g][0], o1[g][1]); dB.y = pack_bf16(o1[g][2], o1[g][3]);
        *(u32x2*)&OpB[pbase + quad * 4] = dA;
        *(u32x2*)&OpB[pbase + 16 + quad * 4] = dB;
        if (quad == 0)
          lpart[((long)ks * 16 + bh) * 4096 + qrow0 + g * 16] = ls;
      }
    }
  }
  __threadfence();
  grid.sync();

  // ---------------- phase 4: key-split reduce (8192 rows) -----------------
  for (int row = bx; row < 8192; row += G) {
    int bq = row >> 12, q = row & 4095;
    int d = tid;
    int h2 = d >> 5, dd = d & 31;
    int bh = bq * 8 + h2;
    float s = 0.f, l = 0.f;
#pragma unroll
    for (int ks = 0; ks < 4; ++ks) {
      long base = (long)(ks * 16 + bh) * 4096 + q;
      s += bf2f(OpB[base * 32 + dd]);
      l += lpart[base];
    }
    attn_out[(long)row * 256 + d] = f2bf(s / l);
  }
  __threadfence();
  grid.sync();

  // ---------------- phase 5: proj GEMM (256 items) -> fp32 out ------------
  {
    short* As = (short*)smem_raw;
    short* Bs = As + 128 * 40;
    const int w = tid >> 6, lane = tid & 63, l16 = lane & 15, quad = lane >> 4;
    const int ar = tid >> 1, ak = (tid & 1) * 16;
    const int br = tid >> 2, bk = (tid & 3) * 8;
    for (int it = bx; it < 256; it += G) {
      int mt = it & 63, nt = it >> 6;
      f32x4 acc[2][4] = {};
      const short* Arow = attn_out + (long)(mt * 128 + ar) * 256 + ak;
      const short* Brow = proj_wt + (long)(nt * 64 + br) * 256 + bk;
      bfrag a8a = *(const bfrag*)Arow;
      bfrag a8b = *(const bfrag*)(Arow + 8);
      bfrag b8  = *(const bfrag*)Brow;
      for (int kk = 0; kk < 8; ++kk) {
        __syncthreads();
        *(bfrag*)&As[ar * 40 + ak] = a8a;
        *(bfrag*)&As[ar * 40 + ak + 8] = a8b;
        *(bfrag*)&Bs[br * 40 + bk] = b8;
        __syncthreads();
        int kn = (kk < 7) ? (kk + 1) : 7;
        a8a = *(const bfrag*)(Arow + kn * 32);
        a8b = *(const bfrag*)(Arow + kn * 32 + 8);
        b8  = *(const bfrag*)(Brow + kn * 32);
        bfrag a0 = *(const bfrag*)&As[(w * 32 + l16) * 40 + quad * 8];
        bfrag a1 = *(const bfrag*)&As[(w * 32 + 16 + l16) * 40 + quad * 8];
#pragma unroll
        for (int c = 0; c < 4; ++c) {
          bfrag bf = *(const bfrag*)&Bs[(c * 16 + l16) * 40 + quad * 8];
          acc[0][c] = __builtin_amdgcn_mfma_f32_16x16x32_bf16(a0, bf, acc[0][c], 0, 0, 0);
          acc[1][c] = __builtin_amdgcn_mfma_f32_16x16x32_bf16(a1, bf, acc[1][c], 0, 0, 0);
        }
      }
      const int rowb = mt * 128 + w * 32 + quad * 4;
#pragma unroll
      for (int rg = 0; rg < 2; ++rg) {
        int row0 = rowb + rg * 16;
#pragma unroll
        for (int c = 0; c < 4; ++c) {
          int col = nt * 64 + c * 16 + l16;
          float bv = proj_b[col];
#pragma unroll
          for (int r = 0; r < 4; ++r)
            out[(long)(row0 + r) * 256 + col] = acc[rg][c][r] + bv;
        }
      }
    }
  }
}

extern "C" void kernel_launch(void* const* d_in, const int* in_sizes, int n_in,
                              void* d_out, int out_size, void* d_ws, size_t ws_size,
                              hipStream_t stream) {
  const float* x      = (const float*)d_in[0];
  // d_in[1] = cond (unused by reference)
  const int*   t      = (const int*)d_in[2];
  const float* emb    = (const float*)d_in[3];
  const float* ada_w  = (const float*)d_in[4];
  const float* ada_b  = (const float*)d_in[5];
  const float* qkv_w  = (const float*)d_in[6];
  const float* qkv_b  = (const float*)d_in[7];
  const float* proj_w = (const float*)d_in[8];
  const float* proj_b = (const float*)d_in[9];
  float* outp = (float*)d_out;

  char* ws = (char*)d_ws;
  float* scsh     = (float*)(ws);                  //   4 KB  [2][512]
  short* qkv_wt   = (short*)(ws + 4096);           // 384 KB  [768][256]
  short* proj_wt  = (short*)(ws + 397312);         // 128 KB  [256][256]
  short* xb       = (short*)(ws + 528384);         //   4 MB  [8192][256]
  short* qk_out   = (short*)(ws + 4722688);        //   8 MB  [8192][512]
  short* vT       = (short*)(ws + 13111296);       //   4 MB  [16][32][4096]
  short* attn_out = (short*)(ws + 17305600);       //   4 MB  [8192][256]
  short* OpB      = (short*)(ws + 21499904);       //  16 MB  [4][16][4096][32] bf16
  float* lpart    = (float*)(ws + 38277120);       //   1 MB  [4][16][4096]

  int nb = 0;
  hipOccupancyMaxActiveBlocksPerMultiprocessor(&nb, (const void*)fused_kernel, 256, 0);
  if (nb < 1) nb = 1;
  long Gl = (long)nb * 256;
  int G = (Gl > 1024) ? 1024 : (int)Gl;
  if (G < 256) G = 256;

  void* args[] = {(void*)&x, (void*)&t, (void*)&emb, (void*)&ada_w, (void*)&ada_b,
                  (void*)&qkv_w, (void*)&qkv_b, (void*)&proj_w, (void*)&proj_b,
                  (void*)&scsh, (void*)&qkv_wt, (void*)&proj_wt, (void*)&xb,
                  (void*)&qk_out, (void*)&vT, (void*)&attn_out, (void*)&OpB,
                  (void*)&lpart, (void*)&outp};
  hipLaunchCooperativeKernel((const void*)fused_kernel, dim3(G), dim3(256),
                             args, 0, stream);
}

// Round 11
// 166.678 us; speedup vs baseline: 4.2324x; 4.2324x over previous
//
#include <hip/hip_runtime.h>
#include <hip/hip_bf16.h>
#include <stdint.h>

typedef __attribute__((ext_vector_type(8))) short bfrag;
typedef __attribute__((ext_vector_type(4))) short bfrag4;
typedef __attribute__((ext_vector_type(4))) float f32x4;
typedef __attribute__((ext_vector_type(2))) float f32x2;
typedef __attribute__((ext_vector_type(2))) unsigned int u32x2;

__device__ inline short f2bf(float f) {
  union { float f; uint32_t u; } v; v.f = f;
  uint32_t u = v.u;
  uint32_t r = (u + 0x7fffu + ((u >> 16) & 1u)) >> 16;
  return (short)r;
}
__device__ inline float bf2f(short s) {
  return __builtin_bit_cast(float, (uint32_t)((uint32_t)(uint16_t)s << 16));
}

#if __has_builtin(__builtin_amdgcn_cvt_pk_bf16_f32)
typedef __attribute__((ext_vector_type(2))) __bf16 bf16x2_t;
__device__ inline uint32_t pack_bf16(float a, float b) {
  bf16x2_t r = __builtin_amdgcn_cvt_pk_bf16_f32(a, b);
  return __builtin_bit_cast(uint32_t, r);
}
#else
__device__ inline uint32_t pack_bf16(float a, float b) {
  uint32_t ua = __builtin_bit_cast(uint32_t, a) + 0x8000u;
  uint32_t ub = __builtin_bit_cast(uint32_t, b) + 0x8000u;
  return __builtin_amdgcn_perm(ub, ua, 0x07060302);
}
#endif

// ---------------- prep: ada (blocks 0-15) + weight transposes (16-79) ------
__global__ __launch_bounds__(256) void prep_kernel(
    const float* __restrict__ emb_table, const int* __restrict__ t,
    const float* __restrict__ ada_w, const float* __restrict__ ada_b,
    float* __restrict__ scsh,
    const float* __restrict__ qkv_w, short* __restrict__ qkv_wt,
    const float* __restrict__ proj_w, short* __restrict__ proj_wt) {
  __shared__ float smem[64 * 65];
  const int blk = blockIdx.x;
  const int tid = threadIdx.x;
  if (blk < 16) {
    float* se = smem;
    float* part = smem + 256;
    int b = blk >> 3, ox = blk & 7;
    int tt = t[b];
    float e = emb_table[tt * 256 + tid];
    se[tid] = e / (1.f + __expf(-e));
    __syncthreads();
    int ol = tid & 63, kc = tid >> 6;
    int o = ox * 64 + ol;
    float acc = 0.f;
#pragma unroll 8
    for (int k = kc * 64; k < (kc + 1) * 64; ++k) acc += se[k] * ada_w[k * 512 + o];
    part[tid] = acc;
    __syncthreads();
    if (tid < 64) {
      int oo = ox * 64 + tid;
      scsh[b * 512 + oo] =
          part[tid] + part[64 + tid] + part[128 + tid] + part[192 + tid] + ada_b[oo];
    }
  } else {
    const float* W; short* Wt; int N, lb;
    if (blk < 64) { W = qkv_w; Wt = qkv_wt; N = 768; lb = blk - 16; }
    else          { W = proj_w; Wt = proj_wt; N = 256; lb = blk - 64; }
    float (*tile)[65] = (float(*)[65])smem;
    int k0 = (lb & 3) * 64, n0 = (lb >> 2) * 64;
    int r = tid >> 2, c0 = (tid & 3) * 16;
    const float* src = W + (long)(k0 + r) * N + n0 + c0;
#pragma unroll
    for (int j = 0; j < 16; j += 4) {
      float4 v = *(const float4*)(src + j);
      tile[r][c0 + j] = v.x; tile[r][c0 + j + 1] = v.y;
      tile[r][c0 + j + 2] = v.z; tile[r][c0 + j + 3] = v.w;
    }
    __syncthreads();
    int nl = tid >> 2, kc = (tid & 3) * 16;
    short outv[16];
#pragma unroll
    for (int j = 0; j < 16; ++j) outv[j] = f2bf(tile[kc + j][nl]);
    short* dst = Wt + (long)(n0 + nl) * 256 + k0 + kc;
    *(bfrag*)dst = *(bfrag*)&outv[0];
    *(bfrag*)(dst + 8) = *(bfrag*)&outv[8];
  }
}

// ---------------- LayerNorm + (1+sc)*xn + sh -> bf16, wave-per-row ---------
__global__ __launch_bounds__(256) void ln_kernel(const float* __restrict__ x,
                                                 const float* __restrict__ scsh,
                                                 short* __restrict__ xb) {
  int row = blockIdx.x * 4 + (threadIdx.x >> 6);   // 2048 blocks x 4 rows
  int b = row >> 12;
  int lane = threadIdx.x & 63;
  float4 v = *(const float4*)(x + (long)row * 256 + lane * 4);
  float s = v.x + v.y + v.z + v.w;
  float sq = v.x * v.x + v.y * v.y + v.z * v.z + v.w * v.w;
#pragma unroll
  for (int off = 32; off > 0; off >>= 1) {
    s += __shfl_xor(s, off);
    sq += __shfl_xor(sq, off);
  }
  float mu = s * (1.f / 256.f);
  float var = sq * (1.f / 256.f) - mu * mu;
  float rstd = rsqrtf(var + 1e-5f);
  const float* scp = scsh + b * 512 + lane * 4;
  float4 sc = *(const float4*)scp;
  float4 sh = *(const float4*)(scp + 256);
  float y0 = (v.x - mu) * rstd * (1.f + sc.x) + sh.x;
  float y1 = (v.y - mu) * rstd * (1.f + sc.y) + sh.y;
  float y2 = (v.z - mu) * rstd * (1.f + sc.z) + sh.z;
  float y3 = (v.w - mu) * rstd * (1.f + sc.w) + sh.w;
  u32x2 o; o.x = pack_bf16(y0, y1); o.y = pack_bf16(y2, y3);
  *(u32x2*)&xb[(long)row * 256 + lane * 4] = o;
}

// ---------------- QKV GEMM, 128x64 tile: qkv = xb * qkv_wt^T + bias --------
// cols 0..511 -> qk bf16 (cols<256 scaled by qscale); 512..767 -> vT (transposed).
__global__ __launch_bounds__(256) void gemm_qkv(const short* __restrict__ A,
                                                const short* __restrict__ Bt,
                                                const float* __restrict__ bias,
                                                float qscale,
                                                short* __restrict__ qk,
                                                short* __restrict__ vT) {
  __shared__ short As[128 * 40];
  __shared__ short Bs[64 * 40];
  const int mt = blockIdx.x, nt = blockIdx.y;
  const int tid = threadIdx.x;
  const int w = tid >> 6, lane = tid & 63, l16 = lane & 15, quad = lane >> 4;
  const int ar = tid >> 1, ak = (tid & 1) * 16;
  const int br = tid >> 2, bk = (tid & 3) * 8;
  f32x4 acc[2][4] = {};
  const short* Arow = A + (long)(mt * 128 + ar) * 256 + ak;
  const short* Brow = Bt + (long)(nt * 64 + br) * 256 + bk;
  bfrag a8a = *(const bfrag*)Arow;
  bfrag a8b = *(const bfrag*)(Arow + 8);
  bfrag b8  = *(const bfrag*)Brow;
  for (int kk = 0; kk < 8; ++kk) {
    __syncthreads();
    *(bfrag*)&As[ar * 40 + ak] = a8a;
    *(bfrag*)&As[ar * 40 + ak + 8] = a8b;
    *(bfrag*)&Bs[br * 40 + bk] = b8;
    __syncthreads();
    int kn = (kk < 7) ? (kk + 1) : 7;
    a8a = *(const bfrag*)(Arow + kn * 32);
    a8b = *(const bfrag*)(Arow + kn * 32 + 8);
    b8  = *(const bfrag*)(Brow + kn * 32);
    bfrag a0 = *(const bfrag*)&As[(w * 32 + l16) * 40 + quad * 8];
    bfrag a1 = *(const bfrag*)&As[(w * 32 + 16 + l16) * 40 + quad * 8];
#pragma unroll
    for (int c = 0; c < 4; ++c) {
      bfrag bf = *(const bfrag*)&Bs[(c * 16 + l16) * 40 + quad * 8];
      acc[0][c] = __builtin_amdgcn_mfma_f32_16x16x32_bf16(a0, bf, acc[0][c], 0, 0, 0);
      acc[1][c] = __builtin_amdgcn_mfma_f32_16x16x32_bf16(a1, bf, acc[1][c], 0, 0, 0);
    }
  }
  const int rowb = mt * 128 + w * 32 + quad * 4;
  if (nt < 8) {  // Q,K columns -> qk pitch 512
#pragma unroll
    for (int rg = 0; rg < 2; ++rg) {
      int row0 = rowb + rg * 16;
#pragma unroll
      for (int c = 0; c < 4; ++c) {
        int col = nt * 64 + c * 16 + l16;
        float bv = bias[col];
        float mult = (col < 256) ? qscale : 1.0f;
#pragma unroll
        for (int r = 0; r < 4; ++r)
          qk[(long)(row0 + r) * 512 + col] = f2bf((acc[rg][c][r] + bv) * mult);
      }
    }
  } else {  // V columns -> vT[bh][d][key]
    const int bb = mt >> 5;
#pragma unroll
    for (int rg = 0; rg < 2; ++rg) {
      int keyl = (rowb + rg * 16) & 4095;
#pragma unroll
      for (int c = 0; c < 4; ++c) {
        int col = nt * 64 + c * 16 + l16;
        float bv = bias[col];
        int d = col - 512;
        u32x2 dd;
        dd.x = pack_bf16(acc[rg][c][0] + bv, acc[rg][c][1] + bv);
        dd.y = pack_bf16(acc[rg][c][2] + bv, acc[rg][c][3] + bv);
        *(u32x2*)&vT[((long)(bb * 8 + (d >> 5)) * 32 + (d & 31)) * 4096 + keyl] = dd;
      }
    }
  }
}

// ---------------- flash attention (S^T scheme, 4 q-groups/wave, ks=4) ------
// Grid: qt(16) x bh(16) x ks(4). Block: 256 q rows, keys [ks*1024, +1024).
__global__ __launch_bounds__(256) void attn_kernel(const short* __restrict__ qk,
                                                   const short* __restrict__ vT,
                                                   short* __restrict__ OpB,
                                                   float* __restrict__ lpart) {
  const int blk = blockIdx.x;
  const int qt = blk & 15;
  const int bh = (blk >> 4) & 15;
  const int ks = blk >> 8;
  const int b = bh >> 3, hh = bh & 7;
  const int tid = threadIdx.x;
  const int w = tid >> 6, lane = tid & 63, l16 = lane & 15, quad = lane >> 4;

  __shared__ short Ks[2][64 * 40];
  __shared__ short Vt[2][32 * 68];

  const long rowbase = (long)b * 4096;
  const int qrow0 = qt * 256 + w * 64 + l16;
  bfrag qf[4];
#pragma unroll
  for (int g = 0; g < 4; ++g)
    qf[g] = *(const bfrag*)&qk[(rowbase + qrow0 + g * 16) * 512 + hh * 32 + quad * 8];

  f32x4 o0[4] = {}, o1[4] = {};
  f32x2 lsum[4] = {};

  const int si = tid >> 2, sk = (tid & 3) * 8;
  const int vrow = tid >> 3, vcol = (tid & 7) * 8;
  const short* ksrc = qk + rowbase * 512 + 256 + hh * 32 + (long)si * 512 + sk;
  const short* vsrc = vT + ((long)bh * 32 + vrow) * 4096 + vcol;

  const int kt0 = ks * 16;
  bfrag k8 = *(const bfrag*)(ksrc + (long)kt0 * 64 * 512);
  bfrag v8 = *(const bfrag*)(vsrc + kt0 * 64);

  int buf = 0;
  for (int i = 0; i < 16; ++i) {
    *(bfrag*)&Ks[buf][si * 40 + sk] = k8;
    *(bfrag*)&Vt[buf][vrow * 68 + vcol] = v8;
    __syncthreads();
    int nn = (i < 15) ? (i + 1) : 15;
    k8 = *(const bfrag*)(ksrc + (long)(kt0 + nn) * 64 * 512);
    v8 = *(const bfrag*)(vsrc + (kt0 + nn) * 64);

#pragma unroll
    for (int nt = 0; nt < 4; ++nt) {
      bfrag kf = *(const bfrag*)&Ks[buf][(nt * 16 + l16) * 40 + quad * 8];
      f32x4 z = {0,0,0,0};
      f32x4 s[4];
      s[0] = __builtin_amdgcn_mfma_f32_16x16x32_bf16(kf, qf[0], z, 0, 0, 0);
      s[1] = __builtin_amdgcn_mfma_f32_16x16x32_bf16(kf, qf[1], z, 0, 0, 0);
      s[2] = __builtin_amdgcn_mfma_f32_16x16x32_bf16(kf, qf[2], z, 0, 0, 0);
      s[3] = __builtin_amdgcn_mfma_f32_16x16x32_bf16(kf, qf[3], z, 0, 0, 0);
      bfrag4 pb[4];
#pragma unroll
      for (int g = 0; g < 4; ++g) {
        float p0 = __builtin_amdgcn_exp2f(s[g][0]);
        float p1 = __builtin_amdgcn_exp2f(s[g][1]);
        float p2 = __builtin_amdgcn_exp2f(s[g][2]);
        float p3 = __builtin_amdgcn_exp2f(s[g][3]);
        f32x2 pa = {p0, p1}, pc = {p2, p3};
        lsum[g] += pa; lsum[g] += pc;
        u32x2 pk; pk.x = pack_bf16(p0, p1); pk.y = pack_bf16(p2, p3);
        pb[g] = __builtin_bit_cast(bfrag4, pk);
      }
      bfrag4 va = *(const bfrag4*)&Vt[buf][l16 * 68 + nt * 16 + quad * 4];
      bfrag4 vb = *(const bfrag4*)&Vt[buf][(16 + l16) * 68 + nt * 16 + quad * 4];
#pragma unroll
      for (int g = 0; g < 4; ++g) {
        o0[g] = __builtin_amdgcn_mfma_f32_16x16x16bf16_1k(va, pb[g], o0[g], 0, 0, 0);
        o1[g] = __builtin_amdgcn_mfma_f32_16x16x16bf16_1k(vb, pb[g], o1[g], 0, 0, 0);
      }
    }
    buf ^= 1;
  }
#pragma unroll
  for (int g = 0; g < 4; ++g) {
    float ls = lsum[g].x + lsum[g].y;
    ls += __shfl_xor(ls, 16); ls += __shfl_xor(ls, 32);
    const long pbase = (((long)ks * 16 + bh) * 4096 + qrow0 + g * 16) * 32;
    u32x2 dA, dB;
    dA.x = pack_bf16(o0[g][0], o0[g][1]); dA.y = pack_bf16(o0[g][2], o0[g][3]);
    dB.x = pack_bf16(o1[g][0], o1[g][1]); dB.y = pack_bf16(o1[g][2], o1[g][3]);
    *(u32x2*)&OpB[pbase + quad * 4] = dA;
    *(u32x2*)&OpB[pbase + 16 + quad * 4] = dB;
    if (quad == 0)
      lpart[((long)ks * 16 + bh) * 4096 + qrow0 + g * 16] = ls;
  }
}

// ---------------- proj GEMM with fused key-split reduce --------------------
// A[row][d] = (sum_ks OpB) / (sum_ks lpart), computed during A-staging.
// Head hh == kk (K-step index): A cols kk*32..+31 come from OpB head kk.
// C = A[8192,256] * proj_wt^T + proj_b -> fp32 out. Grid (64,4), 128x64 tile.
__global__ __launch_bounds__(256) void proj_kernel(const short* __restrict__ OpB,
                                                   const float* __restrict__ lpart,
                                                   const short* __restrict__ Bt,
                                                   const float* __restrict__ bias,
                                                   float* __restrict__ out) {
  __shared__ short As[128 * 40];
  __shared__ short Bs[64 * 40];
  const int mt = blockIdx.x, nt = blockIdx.y;
  const int tid = threadIdx.x;
  const int w = tid >> 6, lane = tid & 63, l16 = lane & 15, quad = lane >> 4;
  const int ar = tid >> 1, ak = (tid & 1) * 16;   // A: 128 rows x 32 cols/iter
  const int br = tid >> 2, bk = (tid & 3) * 8;
  f32x4 acc[2][4] = {};

  const int row = mt * 128 + ar;
  const int q = row & 4095, bq = row >> 12;
  const short* Brow = Bt + (long)(nt * 64 + br) * 256 + bk;

  // prefetch kk=0 (head hh = kk; OpB row index = (ks*16 + bq*8 + kk)*4096 + q)
  long lb0 = (long)(bq * 8) * 4096 + q;
  bfrag pa[4][2];            // [ks][half]: 16 shorts per ks = d ak..ak+15
  f32x4 pl;
#pragma unroll
  for (int ks = 0; ks < 4; ++ks) {
    long base = (lb0 + (long)ks * 16 * 4096) * 32 + ak;
    pa[ks][0] = *(const bfrag*)&OpB[base];
    pa[ks][1] = *(const bfrag*)&OpB[base + 8];
    pl[ks] = lpart[lb0 + (long)ks * 16 * 4096];
  }
  bfrag b8 = *(const bfrag*)Brow;

  for (int kk = 0; kk < 8; ++kk) {
    // combine partials -> bf16 A fragment
    float linv = 1.f / (pl[0] + pl[1] + pl[2] + pl[3]);
    short av[16];
#pragma unroll
    for (int h = 0; h < 2; ++h) {
#pragma unroll
      for (int j = 0; j < 8; j += 2) {
        float v0 = (bf2f(pa[0][h][j]) + bf2f(pa[1][h][j]) +
                    bf2f(pa[2][h][j]) + bf2f(pa[3][h][j])) * linv;
        float v1 = (bf2f(pa[0][h][j+1]) + bf2f(pa[1][h][j+1]) +
                    bf2f(pa[2][h][j+1]) + bf2f(pa[3][h][j+1])) * linv;
        *(uint32_t*)&av[h * 8 + j] = pack_bf16(v0, v1);
      }
    }
    __syncthreads();
    *(bfrag*)&As[ar * 40 + ak] = *(bfrag*)&av[0];
    *(bfrag*)&As[ar * 40 + ak + 8] = *(bfrag*)&av[8];
    *(bfrag*)&Bs[br * 40 + bk] = b8;
    __syncthreads();
    // prefetch next kk
    int kn = (kk < 7) ? (kk + 1) : 7;
    long lbn = (long)(bq * 8 + kn) * 4096 + q;
#pragma unroll
    for (int ks = 0; ks < 4; ++ks) {
      long base = (lbn + (long)ks * 16 * 4096) * 32 + ak;
      pa[ks][0] = *(const bfrag*)&OpB[base];
      pa[ks][1] = *(const bfrag*)&OpB[base + 8];
      pl[ks] = lpart[lbn + (long)ks * 16 * 4096];
    }
    b8 = *(const bfrag*)(Brow + kn * 32);

    bfrag a0 = *(const bfrag*)&As[(w * 32 + l16) * 40 + quad * 8];
    bfrag a1 = *(const bfrag*)&As[(w * 32 + 16 + l16) * 40 + quad * 8];
#pragma unroll
    for (int c = 0; c < 4; ++c) {
      bfrag bf = *(const bfrag*)&Bs[(c * 16 + l16) * 40 + quad * 8];
      acc[0][c] = __builtin_amdgcn_mfma_f32_16x16x32_bf16(a0, bf, acc[0][c], 0, 0, 0);
      acc[1][c] = __builtin_amdgcn_mfma_f32_16x16x32_bf16(a1, bf, acc[1][c], 0, 0, 0);
    }
  }
  const int rowb = mt * 128 + w * 32 + quad * 4;
#pragma unroll
  for (int rg = 0; rg < 2; ++rg) {
    int row0 = rowb + rg * 16;
#pragma unroll
    for (int c = 0; c < 4; ++c) {
      int col = nt * 64 + c * 16 + l16;
      float bv = bias[col];
#pragma unroll
      for (int r = 0; r < 4; ++r)
        out[(long)(row0 + r) * 256 + col] = acc[rg][c][r] + bv;
    }
  }
}

extern "C" void kernel_launch(void* const* d_in, const int* in_sizes, int n_in,
                              void* d_out, int out_size, void* d_ws, size_t ws_size,
                              hipStream_t stream) {
  const float* x      = (const float*)d_in[0];
  // d_in[1] = cond (unused by reference)
  const int*   t      = (const int*)d_in[2];
  const float* emb    = (const float*)d_in[3];
  const float* ada_w  = (const float*)d_in[4];
  const float* ada_b  = (const float*)d_in[5];
  const float* qkv_w  = (const float*)d_in[6];
  const float* qkv_b  = (const float*)d_in[7];
  const float* proj_w = (const float*)d_in[8];
  const float* proj_b = (const float*)d_in[9];

  char* ws = (char*)d_ws;
  float* scsh     = (float*)(ws);                  //   4 KB  [2][512]
  short* qkv_wt   = (short*)(ws + 4096);           // 384 KB  [768][256]
  short* proj_wt  = (short*)(ws + 397312);         // 128 KB  [256][256]
  short* xb       = (short*)(ws + 528384);         //   4 MB  [8192][256]
  short* qk_out   = (short*)(ws + 4722688);        //   8 MB  [8192][512]
  short* vT       = (short*)(ws + 13111296);       //   4 MB  [16][32][4096]
  short* OpB      = (short*)(ws + 21499904);       //  16 MB  [4][16][4096][32] bf16
  float* lpart    = (float*)(ws + 38277120);       //   1 MB  [4][16][4096]

  const float QS = 0.17677669529663687f * 1.4426950408889634f;  // scale*log2e

  prep_kernel<<<80, 256, 0, stream>>>(emb, t, ada_w, ada_b, scsh,
                                      qkv_w, qkv_wt, proj_w, proj_wt);
  ln_kernel<<<2048, 256, 0, stream>>>(x, scsh, xb);
  gemm_qkv<<<dim3(64, 12), 256, 0, stream>>>(xb, qkv_wt, qkv_b, QS, qk_out, vT);
  attn_kernel<<<1024, 256, 0, stream>>>(qk_out, vT, OpB, lpart);
  proj_kernel<<<dim3(64, 4), 256, 0, stream>>>(OpB, lpart, proj_wt, proj_b,
                                               (float*)d_out);
}